// Round 1
// baseline (364.739 us; speedup 1.0000x reference)
//
#include <hip/hip_runtime.h>
#include <math.h>

// Problem constants (from reference): B=65536, F=512, K=1299.
// Key insight: einsum (B,K) + gather == one dot product per row with the
// labeled center. Memory-bound: ~128 MB input stream @ ~6.3 TB/s -> ~21 us.

#define F_DIM 512
#define WAVES_PER_BLOCK 4

__global__ void zero_loss_kernel(float* __restrict__ out) {
    if (threadIdx.x == 0) out[0] = 0.0f;
}

__global__ __launch_bounds__(256) void prediction_loss_kernel(
    const float* __restrict__ input,    // (B, F)
    const float* __restrict__ factor,   // (B, 1)
    const int*   __restrict__ label,    // (B,)
    const float* __restrict__ centers,  // (K, F, 1) == (K, F)
    float* __restrict__ out,            // [0]=loss, [1..B]=predict_a
    int B)
{
    const int wave = threadIdx.x >> 6;
    const int lane = threadIdx.x & 63;
    const int b = blockIdx.x * WAVES_PER_BLOCK + wave;

    __shared__ float partial[WAVES_PER_BLOCK];

    float contrib = 0.0f;
    if (b < B) {
        const int c = label[b];
        // Row base pointers; F_DIM=512 floats = 128 float4s per row.
        const float4* __restrict__ ip =
            (const float4*)(input + (size_t)b * F_DIM);
        const float4* __restrict__ cp =
            (const float4*)(centers + (size_t)c * F_DIM);

        // Each lane: 2 x float4 from input (coalesced 1 KB/wave per load)
        // and matching center elements (L2-resident, 2.66 MB total).
        float4 a0 = ip[lane];
        float4 w0 = cp[lane];
        float4 a1 = ip[lane + 64];
        float4 w1 = cp[lane + 64];

        float dot = a0.x * w0.x + a0.y * w0.y + a0.z * w0.z + a0.w * w0.w
                  + a1.x * w1.x + a1.y * w1.y + a1.z * w1.z + a1.w * w1.w;

        // Wave-64 butterfly reduction.
        #pragma unroll
        for (int off = 32; off > 0; off >>= 1)
            dot += __shfl_xor(dot, off, 64);

        if (lane == 0) {
            float pa = 12.0f * tanhf(dot);
            out[1 + b] = pa;
            float d  = pa - factor[b];
            float ad = fabsf(d);
            float l  = (ad < 1.0f) ? 0.5f * d * d : (ad - 0.5f);
            contrib = l * (1.0f / 65536.0f);  // mean over B
        }
    }

    if (lane == 0) partial[wave] = contrib;
    __syncthreads();
    if (threadIdx.x == 0) {
        float s = partial[0] + partial[1] + partial[2] + partial[3];
        atomicAdd(out, s);  // one atomic per block (16384 total)
    }
}

extern "C" void kernel_launch(void* const* d_in, const int* in_sizes, int n_in,
                              void* d_out, int out_size, void* d_ws, size_t ws_size,
                              hipStream_t stream) {
    const float* input   = (const float*)d_in[0];
    const float* factor  = (const float*)d_in[1];
    const int*   label   = (const int*)d_in[2];
    const float* centers = (const float*)d_in[3];
    float* out = (float*)d_out;

    const int B = in_sizes[1];  // factor has B elements

    // d_out is poisoned 0xAA before every timed launch -> zero the loss slot.
    zero_loss_kernel<<<1, 64, 0, stream>>>(out);

    const int blocks = (B + WAVES_PER_BLOCK - 1) / WAVES_PER_BLOCK;
    prediction_loss_kernel<<<blocks, 256, 0, stream>>>(
        input, factor, label, centers, out, B);
}

// Round 2
// 201.384 us; speedup vs baseline: 1.8112x; 1.8112x over previous
//
#include <hip/hip_runtime.h>
#include <math.h>

// B=65536, F=512, K=1299.
// scores+gather == one dot/row vs labeled center. Memory-bound:
// ~128 MB input stream @ ~6.3 TB/s -> ~21 us floor.
//
// R1 lesson: 16384 same-address atomicAdds serialized at L2 (~13ns each
// = 217us). Now: per-block partials to d_ws + tiny tree-reduce kernel.
// No atomics, no pre-zero kernel.

#define F_DIM 512
#define WAVES_PER_BLOCK 4
#define NUM_BLOCKS 2048            // 8192 waves; 32 waves/CU resident
#define ROWS_PER_WAVE 8            // 65536 / 8192

__global__ __launch_bounds__(256) void prediction_loss_kernel(
    const float* __restrict__ input,    // (B, F)
    const float* __restrict__ factor,   // (B,)
    const int*   __restrict__ label,    // (B,)
    const float* __restrict__ centers,  // (K, F)
    float* __restrict__ out,            // [0]=loss, [1..B]=predict_a
    float* __restrict__ partials,       // (NUM_BLOCKS,)
    int B)
{
    const int wave = threadIdx.x >> 6;
    const int lane = threadIdx.x & 63;
    const int gwave = blockIdx.x * WAVES_PER_BLOCK + wave;  // [0, 8192)

    __shared__ float sh[WAVES_PER_BLOCK];

    // Each wave handles ROWS_PER_WAVE contiguous rows.
    const int b0 = gwave * ROWS_PER_WAVE;

    float acc = 0.0f;  // per-wave loss partial (replicated in all lanes)

    #pragma unroll 2
    for (int r = 0; r < ROWS_PER_WAVE; ++r) {
        const int b = b0 + r;
        // Force the label index scalar so the center base lands in SGPRs.
        const int c = __builtin_amdgcn_readfirstlane(label[b]);

        const float4* __restrict__ ip = (const float4*)(input + (size_t)b * F_DIM);
        const float4* __restrict__ cp = (const float4*)(centers + (size_t)c * F_DIM);

        float4 a0 = ip[lane];
        float4 w0 = cp[lane];
        float4 a1 = ip[lane + 64];
        float4 w1 = cp[lane + 64];

        float dot = a0.x * w0.x + a0.y * w0.y + a0.z * w0.z + a0.w * w0.w
                  + a1.x * w1.x + a1.y * w1.y + a1.z * w1.z + a1.w * w1.w;

        #pragma unroll
        for (int off = 32; off > 0; off >>= 1)
            dot += __shfl_xor(dot, off, 64);
        // All 64 lanes now hold the full dot.

        float pa = 12.0f * tanhf(dot);
        if (lane == 0) out[1 + b] = pa;

        float d  = pa - factor[b];      // broadcast load, single request
        float ad = fabsf(d);
        float l  = (ad < 1.0f) ? 0.5f * d * d : (ad - 0.5f);
        acc += l;
    }

    if (lane == 0) sh[wave] = acc;
    __syncthreads();
    if (threadIdx.x == 0) {
        float s = (sh[0] + sh[1]) + (sh[2] + sh[3]);
        partials[blockIdx.x] = s * (1.0f / 65536.0f);
    }
}

__global__ __launch_bounds__(256) void reduce_partials_kernel(
    const float* __restrict__ partials, float* __restrict__ out)
{
    __shared__ float sh[4];
    const int wave = threadIdx.x >> 6;
    const int lane = threadIdx.x & 63;

    float s = 0.0f;
    #pragma unroll
    for (int i = 0; i < NUM_BLOCKS / 256; ++i)
        s += partials[threadIdx.x + i * 256];

    #pragma unroll
    for (int off = 32; off > 0; off >>= 1)
        s += __shfl_xor(s, off, 64);

    if (lane == 0) sh[wave] = s;
    __syncthreads();
    if (threadIdx.x == 0)
        out[0] = (sh[0] + sh[1]) + (sh[2] + sh[3]);
}

extern "C" void kernel_launch(void* const* d_in, const int* in_sizes, int n_in,
                              void* d_out, int out_size, void* d_ws, size_t ws_size,
                              hipStream_t stream) {
    const float* input   = (const float*)d_in[0];
    const float* factor  = (const float*)d_in[1];
    const int*   label   = (const int*)d_in[2];
    const float* centers = (const float*)d_in[3];
    float* out      = (float*)d_out;
    float* partials = (float*)d_ws;   // NUM_BLOCKS floats, fully overwritten

    const int B = in_sizes[1];  // factor element count

    prediction_loss_kernel<<<NUM_BLOCKS, 256, 0, stream>>>(
        input, factor, label, centers, out, partials, B);
    reduce_partials_kernel<<<1, 256, 0, stream>>>(partials, out);
}

// Round 3
// 197.013 us; speedup vs baseline: 1.8513x; 1.0222x over previous
//
#include <hip/hip_runtime.h>
#include <math.h>

// B=65536, F=512, K=1299.
// einsum+gather == one dot/row vs labeled center. ~128 MB stream -> ~21 us floor.
// R1: same-address atomics serialized (217us). R2: fixed; but per-row serial
// load->reduce->tanh chain left kernel latency-bound (~50us).
// R3: batch 8 rows/wave: 32 float4 loads in flight, ONE batched 6-step
// butterfly (8 independent chains/step), vectorized tanh, lanes 0-7 epilogue.

#define F_DIM 512
#define ROWS_PER_WAVE 8
#define WAVES_PER_BLOCK 4
#define NUM_BLOCKS 2048   // 2048 blk * 4 waves * 8 rows = 65536 rows exactly

__global__ __launch_bounds__(256) void prediction_loss_kernel(
    const float* __restrict__ input,    // (B, F)
    const float* __restrict__ factor,   // (B,)
    const int*   __restrict__ label,    // (B,)
    const float* __restrict__ centers,  // (K, F)
    float* __restrict__ out,            // [0]=loss, [1..B]=predict_a
    float* __restrict__ partials)       // (NUM_BLOCKS,)
{
    const int wave = threadIdx.x >> 6;
    const int lane = threadIdx.x & 63;
    const int gwave = blockIdx.x * WAVES_PER_BLOCK + wave;
    const int b0 = gwave * ROWS_PER_WAVE;

    // --- all label indices first (scalar loads, one indirection level) ---
    int c[ROWS_PER_WAVE];
    #pragma unroll
    for (int r = 0; r < ROWS_PER_WAVE; ++r)
        c[r] = __builtin_amdgcn_readfirstlane(label[b0 + r]);

    // --- issue all 16 input loads (independent, coalesced 1KB/wave each) ---
    float4 a0[ROWS_PER_WAVE], a1[ROWS_PER_WAVE];
    #pragma unroll
    for (int r = 0; r < ROWS_PER_WAVE; ++r) {
        const float4* __restrict__ ip =
            (const float4*)(input + (size_t)(b0 + r) * F_DIM);
        a0[r] = ip[lane];
        a1[r] = ip[lane + 64];
    }
    // --- all 16 center loads (L2/L3-resident, 2.66 MB working set) ---
    float4 w0[ROWS_PER_WAVE], w1[ROWS_PER_WAVE];
    #pragma unroll
    for (int r = 0; r < ROWS_PER_WAVE; ++r) {
        const float4* __restrict__ cp =
            (const float4*)(centers + (size_t)c[r] * F_DIM);
        w0[r] = cp[lane];
        w1[r] = cp[lane + 64];
    }

    // --- 8 independent partial dots ---
    float dot[ROWS_PER_WAVE];
    #pragma unroll
    for (int r = 0; r < ROWS_PER_WAVE; ++r) {
        dot[r] = a0[r].x * w0[r].x + a0[r].y * w0[r].y
               + a0[r].z * w0[r].z + a0[r].w * w0[r].w
               + a1[r].x * w1[r].x + a1[r].y * w1[r].y
               + a1[r].z * w1[r].z + a1[r].w * w1[r].w;
    }

    // --- batched butterfly: 6 steps, 8 independent chains per step ---
    #pragma unroll
    for (int off = 32; off > 0; off >>= 1) {
        #pragma unroll
        for (int r = 0; r < ROWS_PER_WAVE; ++r)
            dot[r] += __shfl_xor(dot[r], off, 64);
    }
    // every lane now holds all 8 complete dots.

    // lane r (r<8) owns row b0+r: branchless select, then one tanh for all.
    const int sel = lane & 7;
    float v = dot[0];
    #pragma unroll
    for (int r = 1; r < ROWS_PER_WAVE; ++r)
        v = (sel == r) ? dot[r] : v;

    const float pa = 12.0f * tanhf(v);

    float contrib = 0.0f;
    if (lane < ROWS_PER_WAVE) {
        out[1 + b0 + lane] = pa;
        const float d  = pa - factor[b0 + lane];
        const float ad = fabsf(d);
        contrib = (ad < 1.0f) ? 0.5f * d * d : (ad - 0.5f);
    }
    // lanes 0-7 nonzero -> reduce within low-3 lane bits only (3 shuffles).
    contrib += __shfl_xor(contrib, 4, 64);
    contrib += __shfl_xor(contrib, 2, 64);
    contrib += __shfl_xor(contrib, 1, 64);

    __shared__ float sh[WAVES_PER_BLOCK];
    if (lane == 0) sh[wave] = contrib;
    __syncthreads();
    if (threadIdx.x == 0)
        partials[blockIdx.x] =
            ((sh[0] + sh[1]) + (sh[2] + sh[3])) * (1.0f / 65536.0f);
}

__global__ __launch_bounds__(256) void reduce_partials_kernel(
    const float* __restrict__ partials, float* __restrict__ out)
{
    __shared__ float sh[4];
    const int wave = threadIdx.x >> 6;
    const int lane = threadIdx.x & 63;

    float s = 0.0f;
    #pragma unroll
    for (int i = 0; i < NUM_BLOCKS / 256; ++i)
        s += partials[threadIdx.x + i * 256];

    #pragma unroll
    for (int off = 32; off > 0; off >>= 1)
        s += __shfl_xor(s, off, 64);

    if (lane == 0) sh[wave] = s;
    __syncthreads();
    if (threadIdx.x == 0)
        out[0] = (sh[0] + sh[1]) + (sh[2] + sh[3]);
}

extern "C" void kernel_launch(void* const* d_in, const int* in_sizes, int n_in,
                              void* d_out, int out_size, void* d_ws, size_t ws_size,
                              hipStream_t stream) {
    const float* input   = (const float*)d_in[0];
    const float* factor  = (const float*)d_in[1];
    const int*   label   = (const int*)d_in[2];
    const float* centers = (const float*)d_in[3];
    float* out      = (float*)d_out;
    float* partials = (float*)d_ws;   // NUM_BLOCKS floats, fully overwritten

    prediction_loss_kernel<<<NUM_BLOCKS, 256, 0, stream>>>(
        input, factor, label, centers, out, partials);
    reduce_partials_kernel<<<1, 256, 0, stream>>>(partials, out);
}

// Round 5
// 195.253 us; speedup vs baseline: 1.8680x; 1.0090x over previous
//
#include <hip/hip_runtime.h>
#include <math.h>

// B=65536, F=512, K=1299.
// einsum+gather == one dot/row vs labeled center.
// R1: same-address atomics serialized (217us kernel). R2: ws partials (~54us).
// R3: batched 8 rows/wave, loads up-front (~50us) — latency chain wasn't it.
// R4 theory: 128 MB input stream evicts the 2.66 MB centers working set from
// L2, so ~96 MB of center re-reads go out past L2. Fix: NON-TEMPORAL input
// loads (nt flag -> evict-first), centers keep normal caching.
// R4 compile fix: __builtin_nontemporal_load needs a native vector type,
// not HIP_vector_type -> use ext_vector_type(4) float.

#define F_DIM 512
#define ROWS_PER_WAVE 8
#define WAVES_PER_BLOCK 4
#define NUM_BLOCKS 2048   // 2048 blk * 4 waves * 8 rows = 65536 rows exactly

typedef float fx4 __attribute__((ext_vector_type(4)));

__global__ __launch_bounds__(256) void prediction_loss_kernel(
    const float* __restrict__ input,    // (B, F)  -- streamed, zero reuse
    const float* __restrict__ factor,   // (B,)
    const int*   __restrict__ label,    // (B,)
    const float* __restrict__ centers,  // (K, F)  -- 2.66 MB, heavy reuse
    float* __restrict__ out,            // [0]=loss, [1..B]=predict_a
    float* __restrict__ partials)       // (NUM_BLOCKS,)
{
    const int wave = threadIdx.x >> 6;
    const int lane = threadIdx.x & 63;
    const int gwave = blockIdx.x * WAVES_PER_BLOCK + wave;
    const int b0 = gwave * ROWS_PER_WAVE;

    // --- all label indices (scalarized) ---
    int c[ROWS_PER_WAVE];
    #pragma unroll
    for (int r = 0; r < ROWS_PER_WAVE; ++r)
        c[r] = __builtin_amdgcn_readfirstlane(label[b0 + r]);

    // --- 16 input loads, NON-TEMPORAL (stream, don't pollute L2) ---
    fx4 a0[ROWS_PER_WAVE], a1[ROWS_PER_WAVE];
    #pragma unroll
    for (int r = 0; r < ROWS_PER_WAVE; ++r) {
        const fx4* __restrict__ ip =
            (const fx4*)(input + (size_t)(b0 + r) * F_DIM);
        a0[r] = __builtin_nontemporal_load(ip + lane);
        a1[r] = __builtin_nontemporal_load(ip + lane + 64);
    }
    // --- 16 center loads, NORMAL caching (L2-resident working set) ---
    fx4 w0[ROWS_PER_WAVE], w1[ROWS_PER_WAVE];
    #pragma unroll
    for (int r = 0; r < ROWS_PER_WAVE; ++r) {
        const fx4* __restrict__ cp =
            (const fx4*)(centers + (size_t)c[r] * F_DIM);
        w0[r] = cp[lane];
        w1[r] = cp[lane + 64];
    }

    // --- 8 independent partial dots ---
    float dot[ROWS_PER_WAVE];
    #pragma unroll
    for (int r = 0; r < ROWS_PER_WAVE; ++r) {
        dot[r] = a0[r].x * w0[r].x + a0[r].y * w0[r].y
               + a0[r].z * w0[r].z + a0[r].w * w0[r].w
               + a1[r].x * w1[r].x + a1[r].y * w1[r].y
               + a1[r].z * w1[r].z + a1[r].w * w1[r].w;
    }

    // --- batched butterfly: 6 steps x 8 independent chains ---
    #pragma unroll
    for (int off = 32; off > 0; off >>= 1) {
        #pragma unroll
        for (int r = 0; r < ROWS_PER_WAVE; ++r)
            dot[r] += __shfl_xor(dot[r], off, 64);
    }
    // every lane holds all 8 complete dots.

    const int sel = lane & 7;
    float v = dot[0];
    #pragma unroll
    for (int r = 1; r < ROWS_PER_WAVE; ++r)
        v = (sel == r) ? dot[r] : v;

    const float pa = 12.0f * tanhf(v);

    float contrib = 0.0f;
    if (lane < ROWS_PER_WAVE) {
        out[1 + b0 + lane] = pa;
        const float d  = pa - factor[b0 + lane];
        const float ad = fabsf(d);
        contrib = (ad < 1.0f) ? 0.5f * d * d : (ad - 0.5f);
    }
    contrib += __shfl_xor(contrib, 4, 64);
    contrib += __shfl_xor(contrib, 2, 64);
    contrib += __shfl_xor(contrib, 1, 64);

    __shared__ float sh[WAVES_PER_BLOCK];
    if (lane == 0) sh[wave] = contrib;
    __syncthreads();
    if (threadIdx.x == 0)
        partials[blockIdx.x] =
            ((sh[0] + sh[1]) + (sh[2] + sh[3])) * (1.0f / 65536.0f);
}

__global__ __launch_bounds__(256) void reduce_partials_kernel(
    const float* __restrict__ partials, float* __restrict__ out)
{
    __shared__ float sh[4];
    const int wave = threadIdx.x >> 6;
    const int lane = threadIdx.x & 63;

    float s = 0.0f;
    #pragma unroll
    for (int i = 0; i < NUM_BLOCKS / 256; ++i)
        s += partials[threadIdx.x + i * 256];

    #pragma unroll
    for (int off = 32; off > 0; off >>= 1)
        s += __shfl_xor(s, off, 64);

    if (lane == 0) sh[wave] = s;
    __syncthreads();
    if (threadIdx.x == 0)
        out[0] = (sh[0] + sh[1]) + (sh[2] + sh[3]);
}

extern "C" void kernel_launch(void* const* d_in, const int* in_sizes, int n_in,
                              void* d_out, int out_size, void* d_ws, size_t ws_size,
                              hipStream_t stream) {
    const float* input   = (const float*)d_in[0];
    const float* factor  = (const float*)d_in[1];
    const int*   label   = (const int*)d_in[2];
    const float* centers = (const float*)d_in[3];
    float* out      = (float*)d_out;
    float* partials = (float*)d_ws;   // NUM_BLOCKS floats, fully overwritten

    prediction_loss_kernel<<<NUM_BLOCKS, 256, 0, stream>>>(
        input, factor, label, centers, out, partials);
    reduce_partials_kernel<<<1, 256, 0, stream>>>(partials, out);
}

// Round 6
// 192.700 us; speedup vs baseline: 1.8928x; 1.0133x over previous
//
#include <hip/hip_runtime.h>
#include <math.h>

// B=65536, F=512, K=1299.
// einsum+gather == one dot/row vs labeled center.
// R1: same-address atomics serialize @13.3ns each (217us). R2: ws partials.
// R3: batched rows/wave (~50us kernel). R4/R5: nt loads neutral -> cache
// eviction theory refuted. Fixed harness reset ~145us (512MB poison + 131MB
// restore) dominates total; controllable = main(~43us) + reduce(~5us).
// R6: occupancy experiment - ROWS_PER_WAVE 8->4 halves data VGPRs
// (~5 waves/SIMD instead of ~3), 2x blocks. Discriminates latency-bound (a)
// vs external reset-writeback interference (b). Fusion via last-block
// counter rejected: 4096 atomics x 13ns = 54us tail > 5us dispatch saved.

#define F_DIM 512
#define ROWS_PER_WAVE 4
#define WAVES_PER_BLOCK 4
#define NUM_BLOCKS 4096   // 4096 blk * 4 waves * 4 rows = 65536 rows exactly

typedef float fx4 __attribute__((ext_vector_type(4)));

__global__ __launch_bounds__(256) void prediction_loss_kernel(
    const float* __restrict__ input,    // (B, F)  -- streamed, zero reuse
    const float* __restrict__ factor,   // (B,)
    const int*   __restrict__ label,    // (B,)
    const float* __restrict__ centers,  // (K, F)  -- 2.66 MB, heavy reuse
    float* __restrict__ out,            // [0]=loss, [1..B]=predict_a
    float* __restrict__ partials)       // (NUM_BLOCKS,)
{
    const int wave = threadIdx.x >> 6;
    const int lane = threadIdx.x & 63;
    const int b0 = (blockIdx.x * WAVES_PER_BLOCK + wave) * ROWS_PER_WAVE;

    // --- label indices (scalarized) ---
    int c[ROWS_PER_WAVE];
    #pragma unroll
    for (int r = 0; r < ROWS_PER_WAVE; ++r)
        c[r] = __builtin_amdgcn_readfirstlane(label[b0 + r]);

    // --- 8 input loads, non-temporal (stream, no reuse) ---
    fx4 a0[ROWS_PER_WAVE], a1[ROWS_PER_WAVE];
    #pragma unroll
    for (int r = 0; r < ROWS_PER_WAVE; ++r) {
        const fx4* __restrict__ ip =
            (const fx4*)(input + (size_t)(b0 + r) * F_DIM);
        a0[r] = __builtin_nontemporal_load(ip + lane);
        a1[r] = __builtin_nontemporal_load(ip + lane + 64);
    }
    // --- 8 center loads, normal caching ---
    fx4 w0[ROWS_PER_WAVE], w1[ROWS_PER_WAVE];
    #pragma unroll
    for (int r = 0; r < ROWS_PER_WAVE; ++r) {
        const fx4* __restrict__ cp =
            (const fx4*)(centers + (size_t)c[r] * F_DIM);
        w0[r] = cp[lane];
        w1[r] = cp[lane + 64];
    }

    // --- 4 independent partial dots ---
    float dot[ROWS_PER_WAVE];
    #pragma unroll
    for (int r = 0; r < ROWS_PER_WAVE; ++r) {
        dot[r] = a0[r].x * w0[r].x + a0[r].y * w0[r].y
               + a0[r].z * w0[r].z + a0[r].w * w0[r].w
               + a1[r].x * w1[r].x + a1[r].y * w1[r].y
               + a1[r].z * w1[r].z + a1[r].w * w1[r].w;
    }

    // --- batched butterfly: 6 steps x 4 independent chains ---
    #pragma unroll
    for (int off = 32; off > 0; off >>= 1) {
        #pragma unroll
        for (int r = 0; r < ROWS_PER_WAVE; ++r)
            dot[r] += __shfl_xor(dot[r], off, 64);
    }
    // every lane holds all 4 complete dots.

    const int sel = lane & 3;
    float v = dot[0];
    #pragma unroll
    for (int r = 1; r < ROWS_PER_WAVE; ++r)
        v = (sel == r) ? dot[r] : v;

    const float pa = 12.0f * tanhf(v);

    float contrib = 0.0f;
    if (lane < ROWS_PER_WAVE) {
        out[1 + b0 + lane] = pa;
        const float d  = pa - factor[b0 + lane];
        const float ad = fabsf(d);
        contrib = (ad < 1.0f) ? 0.5f * d * d : (ad - 0.5f);
    }
    contrib += __shfl_xor(contrib, 2, 64);
    contrib += __shfl_xor(contrib, 1, 64);

    __shared__ float sh[WAVES_PER_BLOCK];
    if (lane == 0) sh[wave] = contrib;
    __syncthreads();
    if (threadIdx.x == 0)
        partials[blockIdx.x] =
            ((sh[0] + sh[1]) + (sh[2] + sh[3])) * (1.0f / 65536.0f);
}

__global__ __launch_bounds__(256) void reduce_partials_kernel(
    const float* __restrict__ partials, float* __restrict__ out)
{
    __shared__ float sh[4];
    const int wave = threadIdx.x >> 6;
    const int lane = threadIdx.x & 63;

    float s = 0.0f;
    #pragma unroll
    for (int i = 0; i < NUM_BLOCKS / 256; ++i)
        s += partials[threadIdx.x + i * 256];

    #pragma unroll
    for (int off = 32; off > 0; off >>= 1)
        s += __shfl_xor(s, off, 64);

    if (lane == 0) sh[wave] = s;
    __syncthreads();
    if (threadIdx.x == 0)
        out[0] = (sh[0] + sh[1]) + (sh[2] + sh[3]);
}

extern "C" void kernel_launch(void* const* d_in, const int* in_sizes, int n_in,
                              void* d_out, int out_size, void* d_ws, size_t ws_size,
                              hipStream_t stream) {
    const float* input   = (const float*)d_in[0];
    const float* factor  = (const float*)d_in[1];
    const int*   label   = (const int*)d_in[2];
    const float* centers = (const float*)d_in[3];
    float* out      = (float*)d_out;
    float* partials = (float*)d_ws;   // NUM_BLOCKS floats, fully overwritten

    prediction_loss_kernel<<<NUM_BLOCKS, 256, 0, stream>>>(
        input, factor, label, centers, out, partials);
    reduce_partials_kernel<<<1, 256, 0, stream>>>(partials, out);
}